// Round 13
// baseline (88411.688 us; speedup 1.0000x reference)
//
#include <hip/hip_runtime.h>
#include <hip/hip_bf16.h>
#include <stdint.h>

#define T_STEPS 32768
#define HID 1024
#define FIN 256
#define NB_SCAN 16       // scan blocks (halved: fewer pollers -> less MALL contention)
#define NB_HEAT 28       // PURE-FMA clock-heater blocks (R12 config)
#define NWAVE 8          // waves per scan block
#define RPB 64           // rows per scan block
#define RPW 8            // rows per wave
#define WORDS (HID / 2)  // packed 8B words per h vector = 512

typedef unsigned long long ull;

// ---------------- Phase 1: xw[t][h] = sum_k x[t][k] * wih[h][k] ----------------
__global__ __launch_bounds__(256) void gemm_xw(const float* __restrict__ x,
                                               const float* __restrict__ wih,
                                               float* __restrict__ out) {
    __shared__ float As[32][132];
    __shared__ float Bs[32][132];
    const int tid = threadIdx.x;
    const int m0 = blockIdx.y * 128;
    const int n0 = blockIdx.x * 128;
    const int tm = tid >> 4, tn = tid & 15;
    const int lr = tid >> 1, lc = (tid & 1) * 16;

    float acc[8][8];
#pragma unroll
    for (int i = 0; i < 8; ++i)
#pragma unroll
        for (int j = 0; j < 8; ++j) acc[i][j] = 0.f;

    for (int kk = 0; kk < FIN; kk += 32) {
#pragma unroll
        for (int u = 0; u < 4; ++u) {
            float4 av = *reinterpret_cast<const float4*>(
                &x[(size_t)(m0 + lr) * FIN + kk + lc + 4 * u]);
            float4 bv = *reinterpret_cast<const float4*>(
                &wih[(size_t)(n0 + lr) * FIN + kk + lc + 4 * u]);
            As[lc + 4 * u + 0][lr] = av.x;
            As[lc + 4 * u + 1][lr] = av.y;
            As[lc + 4 * u + 2][lr] = av.z;
            As[lc + 4 * u + 3][lr] = av.w;
            Bs[lc + 4 * u + 0][lr] = bv.x;
            Bs[lc + 4 * u + 1][lr] = bv.y;
            Bs[lc + 4 * u + 2][lr] = bv.z;
            Bs[lc + 4 * u + 3][lr] = bv.w;
        }
        __syncthreads();
#pragma unroll
        for (int k = 0; k < 32; ++k) {
            const float4* Ak = reinterpret_cast<const float4*>(&As[k][0]);
            const float4* Bk = reinterpret_cast<const float4*>(&Bs[k][0]);
            float4 a0 = Ak[tm * 2], a1 = Ak[tm * 2 + 1];
            float4 b0 = Bk[tn * 2], b1 = Bk[tn * 2 + 1];
            float a[8] = {a0.x, a0.y, a0.z, a0.w, a1.x, a1.y, a1.z, a1.w};
            float b[8] = {b0.x, b0.y, b0.z, b0.w, b1.x, b1.y, b1.z, b1.w};
#pragma unroll
            for (int i = 0; i < 8; ++i)
#pragma unroll
                for (int j = 0; j < 8; ++j) acc[i][j] = fmaf(a[i], b[j], acc[i][j]);
        }
        __syncthreads();
    }
#pragma unroll
    for (int i = 0; i < 8; ++i) {
        float4 o0 = make_float4(acc[i][0], acc[i][1], acc[i][2], acc[i][3]);
        float4 o1 = make_float4(acc[i][4], acc[i][5], acc[i][6], acc[i][7]);
        float* op = &out[(size_t)(m0 + tm * 8 + i) * HID + n0 + tn * 8];
        *reinterpret_cast<float4*>(op) = o0;
        *reinterpret_cast<float4*>(op + 4) = o1;
    }
}

// ---------------- Phase 2: persistent serial scan + pure-FMA heaters ----------------
__device__ __forceinline__ float fast_tanh(float x) {
    float cx = fminf(fmaxf(x, -16.f), 16.f);
    float e = __builtin_amdgcn_exp2f(cx * 2.8853900817779268f);
    return (e - 1.f) * __builtin_amdgcn_rcpf(e + 1.f);
}

__device__ __forceinline__ void poll8(const ull* __restrict__ src, int lane,
                                      ull (&v)[8]) {
#pragma unroll
    for (int i = 0; i < 8; ++i)
        v[i] = __hip_atomic_load(src + lane + 64 * i, __ATOMIC_RELAXED,
                                 __HIP_MEMORY_SCOPE_AGENT);
}

__device__ __forceinline__ bool check8(const ull (&v)[8], unsigned expb) {
    unsigned d = 0;
#pragma unroll
    for (int i = 0; i < 8; ++i) d |= (((unsigned)v[i]) ^ expb) & 0xFFu;
    return d == 0;
}

// PURE-FMA heater (R12): zero memory traffic; bounded; quit-flag polled.
__device__ void heater_body(const int* quit, int tid) {
    float a0 = tid * 0.001f + 1.f, a1 = a0 + 1.f, a2 = a0 + 2.f, a3 = a0 + 3.f;
    float a4 = a0 + 4.f, a5 = a0 + 5.f, a6 = a0 + 6.f, a7 = a0 + 7.f;
    for (int it = 0; it < 300000; ++it) {  // hard cap, always terminates
#pragma unroll 64
        for (int u = 0; u < 64; ++u) {
            a0 = fmaf(a0, 1.0000001f, 0.5f);
            a1 = fmaf(a1, 1.0000001f, 0.5f);
            a2 = fmaf(a2, 1.0000001f, 0.5f);
            a3 = fmaf(a3, 1.0000001f, 0.5f);
            a4 = fmaf(a4, 1.0000001f, 0.5f);
            a5 = fmaf(a5, 1.0000001f, 0.5f);
            a6 = fmaf(a6, 1.0000001f, 0.5f);
            a7 = fmaf(a7, 1.0000001f, 0.5f);
        }
        if (__hip_atomic_load(quit, __ATOMIC_RELAXED, __HIP_MEMORY_SCOPE_AGENT))
            break;
    }
    asm volatile("" ::"v"(a0), "v"(a1), "v"(a2), "v"(a3), "v"(a4), "v"(a5),
                 "v"(a6), "v"(a7));
}

// Transport = R7/R12 protocol verbatim; ONLY change: 16 blocks x 8 waves
// (was 32 x 4). Each wave still computes 8 rows (identical shape); wave0
// dual-role polls all 512 words. Halves pollers: 16x512 poll loads/step
// instead of 32x512 on the same 64 MALL lines.
//  Safety (unchanged): wave0 overwrites hshw for step t only after ALL 512
//  tags==t, which includes THIS block's words, which its 8 waves store only
//  after consuming hshw of step t-1.
__global__ __launch_bounds__(512, 1) void scan_rnn(
    const float* __restrict__ whh, const float* __restrict__ wgt,
    const float* __restrict__ bih, const float* __restrict__ bhh,
    const float* __restrict__ bb, float* __restrict__ out,
    ull* __restrict__ hbuf, int* __restrict__ quit) {
    if (blockIdx.x >= NB_SCAN) {
        heater_body(quit, threadIdx.x);
        return;
    }
    __shared__ ull hshw[WORDS];
    const int lane = threadIdx.x & 63;
    const int wv = threadIdx.x >> 6;
    const int r0 = blockIdx.x * RPB + wv * RPW;
    const int rr = r0 + (lane & 7);

    // W_hh slice: lane covers k = lane + 64*i
    float wreg[RPW][16];
#pragma unroll
    for (int j = 0; j < RPW; ++j)
#pragma unroll
        for (int i = 0; i < 16; ++i)
            wreg[j][i] = whh[(size_t)(r0 + j) * HID + lane + 64 * i];

    const float cw = wgt[rr], cbi = bih[rr], cbh = bhh[rr], cb = bb[rr];
    float xw_cur = out[rr];  // xw row 0 (scan launches after gemm)

    for (int t = 0; t < T_STEPS; ++t) {
        if (wv == 0) {
            // tag-in-data poll: detect == data, no extra RT
            const ull* src = hbuf + (size_t)(t & 1) * WORDS;
            const unsigned expb = (unsigned)t & 0xFFu;
            ull va[8], vb[8];
            poll8(src, lane, va);
            for (;;) {
                poll8(src, lane, vb);
                if (check8(va, expb)) {
#pragma unroll
                    for (int i = 0; i < 8; ++i) hshw[lane + 64 * i] = va[i];
                    break;
                }
                poll8(src, lane, va);
                if (check8(vb, expb)) {
#pragma unroll
                    for (int i = 0; i < 8; ++i) hshw[lane + 64 * i] = vb[i];
                    break;
                }
                __builtin_amdgcn_s_sleep(1);
            }
        }
        __syncthreads();  // h_t available in LDS (packed words == f32[1024])

        const float* hf = (const float*)(&hshw[0]);
        float hval[16];
#pragma unroll
        for (int i = 0; i < 16; ++i) hval[i] = hf[lane + 64 * i];

        float acc[RPW];
#pragma unroll
        for (int j = 0; j < RPW; ++j) acc[j] = 0.f;
#pragma unroll
        for (int i = 0; i < 16; ++i)
#pragma unroll
            for (int j = 0; j < RPW; ++j)
                acc[j] = fmaf(wreg[j][i], hval[i], acc[j]);

        // 3 stages x8, select own row, 3 stages x1
#pragma unroll
        for (int m = 1; m < 8; m <<= 1)
#pragma unroll
            for (int j = 0; j < RPW; ++j) acc[j] += __shfl_xor(acc[j], m, 64);
        float y = acc[0];
#pragma unroll
        for (int j = 1; j < RPW; ++j) y = ((lane & 7) == j) ? acc[j] : y;
#pragma unroll
        for (int m = 8; m < 64; m <<= 1) y += __shfl_xor(y, m, 64);

        const float arg = fmaf(fmaf(cw, xw_cur, cbh), y, fmaf(cbi, xw_cur, cb));
        const float hn = fast_tanh(arg);
        const float hnp = __shfl_xor(hn, 1, 64);  // partner (odd) row's value

        if (lane < 8) {
            if ((lane & 1) == 0) {
                // tagged packed store FIRST (critical path)
                unsigned lo = (__float_as_uint(hn) & 0xFFFFFF00u) |
                              ((unsigned)(t + 1) & 0xFFu);
                ull pv = ((ull)__float_as_uint(hnp) << 32) | (ull)lo;
                __hip_atomic_store(
                    hbuf + (size_t)((t + 1) & 1) * WORDS + (r0 >> 1) +
                        (lane >> 1),
                    pv, __ATOMIC_RELAXED, __HIP_MEMORY_SCOPE_AGENT);
            }
            out[(size_t)t * HID + rr] = hn;  // result store, off critical path
        }
        // prefetch next xw; HBM latency hides under inter-step wait
        const int nt = t < T_STEPS - 1 ? t + 1 : t;
        xw_cur = out[(size_t)nt * HID + rr];
    }
    if (blockIdx.x == 0 && threadIdx.x == 0)
        __hip_atomic_store(quit, 1, __ATOMIC_RELAXED, __HIP_MEMORY_SCOPE_AGENT);
}

extern "C" void kernel_launch(void* const* d_in, const int* in_sizes, int n_in,
                              void* d_out, int out_size, void* d_ws, size_t ws_size,
                              hipStream_t stream) {
    const float* x = (const float*)d_in[0];    // [T,1,256]
    const float* wih = (const float*)d_in[1];  // [1024,256]
    const float* whh = (const float*)d_in[2];  // [1024,1024]
    const float* wgt = (const float*)d_in[3];  // [1024]
    const float* bih = (const float*)d_in[4];
    const float* bhh = (const float*)d_in[5];
    const float* bb = (const float*)d_in[6];
    float* out = (float*)d_out;  // [T,1,1024] f32; holds xw between phases

    ull* hbuf = (ull*)d_ws;  // 2*512*8B = 8 KiB
    int* quit = (int*)((char*)d_ws + 2 * WORDS * sizeof(ull));
    hipMemsetAsync(d_ws, 0, 2 * WORDS * sizeof(ull) + 128, stream);

    dim3 ggrid(HID / 128, T_STEPS / 128);
    gemm_xw<<<ggrid, 256, 0, stream>>>(x, wih, out);

    scan_rnn<<<NB_SCAN + NB_HEAT, 512, 0, stream>>>(whh, wgt, bih, bhh, bb,
                                                    out, hbuf, quit);
}

// Round 14
// 64704.626 us; speedup vs baseline: 1.3664x; 1.3664x over previous
//
#include <hip/hip_runtime.h>
#include <hip/hip_bf16.h>
#include <stdint.h>

#define T_STEPS 32768
#define HID 1024
#define FIN 256
#define NB_SCAN 32       // scan blocks (32 x 4 proven shape)
#define NB_HEAT 28       // PURE-FMA clock-heater blocks (R12 config)
#define RPB 32           // rows per scan block
#define RPW 8            // rows per wave (4 waves/block)
#define WORDS (HID / 2)  // packed 8B words per h vector = 512

typedef unsigned long long ull;

// ---------------- Phase 1: xw[t][h] = sum_k x[t][k] * wih[h][k] ----------------
__global__ __launch_bounds__(256) void gemm_xw(const float* __restrict__ x,
                                               const float* __restrict__ wih,
                                               float* __restrict__ out) {
    __shared__ float As[32][132];
    __shared__ float Bs[32][132];
    const int tid = threadIdx.x;
    const int m0 = blockIdx.y * 128;
    const int n0 = blockIdx.x * 128;
    const int tm = tid >> 4, tn = tid & 15;
    const int lr = tid >> 1, lc = (tid & 1) * 16;

    float acc[8][8];
#pragma unroll
    for (int i = 0; i < 8; ++i)
#pragma unroll
        for (int j = 0; j < 8; ++j) acc[i][j] = 0.f;

    for (int kk = 0; kk < FIN; kk += 32) {
#pragma unroll
        for (int u = 0; u < 4; ++u) {
            float4 av = *reinterpret_cast<const float4*>(
                &x[(size_t)(m0 + lr) * FIN + kk + lc + 4 * u]);
            float4 bv = *reinterpret_cast<const float4*>(
                &wih[(size_t)(n0 + lr) * FIN + kk + lc + 4 * u]);
            As[lc + 4 * u + 0][lr] = av.x;
            As[lc + 4 * u + 1][lr] = av.y;
            As[lc + 4 * u + 2][lr] = av.z;
            As[lc + 4 * u + 3][lr] = av.w;
            Bs[lc + 4 * u + 0][lr] = bv.x;
            Bs[lc + 4 * u + 1][lr] = bv.y;
            Bs[lc + 4 * u + 2][lr] = bv.z;
            Bs[lc + 4 * u + 3][lr] = bv.w;
        }
        __syncthreads();
#pragma unroll
        for (int k = 0; k < 32; ++k) {
            const float4* Ak = reinterpret_cast<const float4*>(&As[k][0]);
            const float4* Bk = reinterpret_cast<const float4*>(&Bs[k][0]);
            float4 a0 = Ak[tm * 2], a1 = Ak[tm * 2 + 1];
            float4 b0 = Bk[tn * 2], b1 = Bk[tn * 2 + 1];
            float a[8] = {a0.x, a0.y, a0.z, a0.w, a1.x, a1.y, a1.z, a1.w};
            float b[8] = {b0.x, b0.y, b0.z, b0.w, b1.x, b1.y, b1.z, b1.w};
#pragma unroll
            for (int i = 0; i < 8; ++i)
#pragma unroll
                for (int j = 0; j < 8; ++j) acc[i][j] = fmaf(a[i], b[j], acc[i][j]);
        }
        __syncthreads();
    }
#pragma unroll
    for (int i = 0; i < 8; ++i) {
        float4 o0 = make_float4(acc[i][0], acc[i][1], acc[i][2], acc[i][3]);
        float4 o1 = make_float4(acc[i][4], acc[i][5], acc[i][6], acc[i][7]);
        float* op = &out[(size_t)(m0 + tm * 8 + i) * HID + n0 + tn * 8];
        *reinterpret_cast<float4*>(op) = o0;
        *reinterpret_cast<float4*>(op + 4) = o1;
    }
}

// ---------------- Phase 2: persistent serial scan + pure-FMA heaters ----------------
__device__ __forceinline__ float fast_tanh(float x) {
    float cx = fminf(fmaxf(x, -16.f), 16.f);
    float e = __builtin_amdgcn_exp2f(cx * 2.8853900817779268f);
    return (e - 1.f) * __builtin_amdgcn_rcpf(e + 1.f);
}

__device__ __forceinline__ void poll8(const ull* __restrict__ src, int lane,
                                      ull (&v)[8]) {
#pragma unroll
    for (int i = 0; i < 8; ++i)
        v[i] = __hip_atomic_load(src + lane + 64 * i, __ATOMIC_RELAXED,
                                 __HIP_MEMORY_SCOPE_AGENT);
}

__device__ __forceinline__ bool check8(const ull (&v)[8], unsigned expb) {
    unsigned d = 0;
#pragma unroll
    for (int i = 0; i < 8; ++i) d |= (((unsigned)v[i]) ^ expb) & 0xFFu;
    return d == 0;
}

// PURE-FMA heater (R12): zero memory traffic; bounded; quit-flag polled.
__device__ void heater_body(const int* quit, int tid) {
    float a0 = tid * 0.001f + 1.f, a1 = a0 + 1.f, a2 = a0 + 2.f, a3 = a0 + 3.f;
    float a4 = a0 + 4.f, a5 = a0 + 5.f, a6 = a0 + 6.f, a7 = a0 + 7.f;
    for (int it = 0; it < 300000; ++it) {  // hard cap, always terminates
#pragma unroll 64
        for (int u = 0; u < 64; ++u) {
            a0 = fmaf(a0, 1.0000001f, 0.5f);
            a1 = fmaf(a1, 1.0000001f, 0.5f);
            a2 = fmaf(a2, 1.0000001f, 0.5f);
            a3 = fmaf(a3, 1.0000001f, 0.5f);
            a4 = fmaf(a4, 1.0000001f, 0.5f);
            a5 = fmaf(a5, 1.0000001f, 0.5f);
            a6 = fmaf(a6, 1.0000001f, 0.5f);
            a7 = fmaf(a7, 1.0000001f, 0.5f);
        }
        if (__hip_atomic_load(quit, __ATOMIC_RELAXED, __HIP_MEMORY_SCOPE_AGENT))
            break;
    }
    asm volatile("" ::"v"(a0), "v"(a1), "v"(a2), "v"(a3), "v"(a4), "v"(a5),
                 "v"(a6), "v"(a7));
}

// Transport = R7/R12 protocol with ONE structural change: h is REPLICATED
// into 32 per-consumer private buffers.
//   hbuf[parity][consumer][512 words]; block b writes words [16b..16b+16)
//   of EVERY consumer's buffer (2 lines per (writer,consumer) pair) ->
//   every 64B line has exactly 1 writer block and 1 reader block. This
//   removes the 32-readers-per-line poll storm that queued ahead of
//   producer stores (R2->R3 dedup win + R13 shape-exoneration evidence).
// Producer epilogue: the 4 packed words of a wave are rebuilt per-lane via
// width-8 shuffles; each of the 64 lanes stores ONE word to TWO consumers
// (128 stores/wave, all distinct lines). Tags (low mantissa byte = t+1 mod
// 256) self-validate each word -> safety identical to R7.
__global__ __launch_bounds__(256, 1) void scan_rnn(
    const float* __restrict__ whh, const float* __restrict__ wgt,
    const float* __restrict__ bih, const float* __restrict__ bhh,
    const float* __restrict__ bb, float* __restrict__ out,
    ull* __restrict__ hbuf, int* __restrict__ quit) {
    if (blockIdx.x >= NB_SCAN) {
        heater_body(quit, threadIdx.x);
        return;
    }
    __shared__ ull hshw[WORDS];
    const int lane = threadIdx.x & 63;
    const int wv = threadIdx.x >> 6;
    const int r0 = blockIdx.x * RPB + wv * RPW;
    const int rr = r0 + (lane & 7);

    // W_hh slice: lane covers k = lane + 64*i
    float wreg[RPW][16];
#pragma unroll
    for (int j = 0; j < RPW; ++j)
#pragma unroll
        for (int i = 0; i < 16; ++i)
            wreg[j][i] = whh[(size_t)(r0 + j) * HID + lane + 64 * i];

    const float cw = wgt[rr], cbi = bih[rr], cbh = bhh[rr], cb = bb[rr];
    float xw_cur = out[rr];  // xw row 0 (scan launches after gemm)

    for (int t = 0; t < T_STEPS; ++t) {
        if (wv == 0) {
            // poll OWN private buffer (tag-in-data; detect == data)
            const ull* src =
                hbuf + ((size_t)(t & 1) * NB_SCAN + blockIdx.x) * WORDS;
            const unsigned expb = (unsigned)t & 0xFFu;
            ull va[8], vb[8];
            poll8(src, lane, va);
            for (;;) {
                poll8(src, lane, vb);
                if (check8(va, expb)) {
#pragma unroll
                    for (int i = 0; i < 8; ++i) hshw[lane + 64 * i] = va[i];
                    break;
                }
                poll8(src, lane, va);
                if (check8(vb, expb)) {
#pragma unroll
                    for (int i = 0; i < 8; ++i) hshw[lane + 64 * i] = vb[i];
                    break;
                }
                __builtin_amdgcn_s_sleep(1);
            }
        }
        __syncthreads();  // h_t available in LDS (packed words == f32[1024])

        const float* hf = (const float*)(&hshw[0]);
        float hval[16];
#pragma unroll
        for (int i = 0; i < 16; ++i) hval[i] = hf[lane + 64 * i];

        float acc[RPW];
#pragma unroll
        for (int j = 0; j < RPW; ++j) acc[j] = 0.f;
#pragma unroll
        for (int i = 0; i < 16; ++i)
#pragma unroll
            for (int j = 0; j < RPW; ++j)
                acc[j] = fmaf(wreg[j][i], hval[i], acc[j]);

        // 3 stages x8, select own row, 3 stages x1
#pragma unroll
        for (int m = 1; m < 8; m <<= 1)
#pragma unroll
            for (int j = 0; j < RPW; ++j) acc[j] += __shfl_xor(acc[j], m, 64);
        float y = acc[0];
#pragma unroll
        for (int j = 1; j < RPW; ++j) y = ((lane & 7) == j) ? acc[j] : y;
#pragma unroll
        for (int m = 8; m < 64; m <<= 1) y += __shfl_xor(y, m, 64);

        const float arg = fmaf(fmaf(cw, xw_cur, cbh), y, fmaf(cbi, xw_cur, cb));
        const float hn = fast_tanh(arg);

        // ---- replicated tagged publish (critical path) ----
        // wave's 8 rows -> 4 packed words; j = lane&3 selects word (rows
        // 2j,2j+1 via width-8 shuffle); each lane stores word j to consumers
        // (lane>>2) and (lane>>2)+16.
        {
            const int j = lane & 3;
            const float lo_f = __shfl(hn, 2 * j, 8);
            const float hi_f = __shfl(hn, 2 * j + 1, 8);
            const unsigned tagb = (unsigned)(t + 1) & 0xFFu;
            const unsigned lo = (__float_as_uint(lo_f) & 0xFFFFFF00u) | tagb;
            const ull pv = ((ull)__float_as_uint(hi_f) << 32) | (ull)lo;
            const int widx = (r0 >> 1) + j;  // word index in [0,512)
            ull* dstbase =
                hbuf + (size_t)((t + 1) & 1) * NB_SCAN * WORDS + widx;
            const int cons = lane >> 2;  // 0..15
            __hip_atomic_store(dstbase + (size_t)cons * WORDS, pv,
                               __ATOMIC_RELAXED, __HIP_MEMORY_SCOPE_AGENT);
            __hip_atomic_store(dstbase + (size_t)(cons + 16) * WORDS, pv,
                               __ATOMIC_RELAXED, __HIP_MEMORY_SCOPE_AGENT);
        }
        if (lane < 8) out[(size_t)t * HID + rr] = hn;  // off critical path
        // prefetch next xw; HBM latency hides under inter-step wait
        const int nt = t < T_STEPS - 1 ? t + 1 : t;
        xw_cur = out[(size_t)nt * HID + rr];
    }
    if (blockIdx.x == 0 && threadIdx.x == 0)
        __hip_atomic_store(quit, 1, __ATOMIC_RELAXED, __HIP_MEMORY_SCOPE_AGENT);
}

extern "C" void kernel_launch(void* const* d_in, const int* in_sizes, int n_in,
                              void* d_out, int out_size, void* d_ws, size_t ws_size,
                              hipStream_t stream) {
    const float* x = (const float*)d_in[0];    // [T,1,256]
    const float* wih = (const float*)d_in[1];  // [1024,256]
    const float* whh = (const float*)d_in[2];  // [1024,1024]
    const float* wgt = (const float*)d_in[3];  // [1024]
    const float* bih = (const float*)d_in[4];
    const float* bhh = (const float*)d_in[5];
    const float* bb = (const float*)d_in[6];
    float* out = (float*)d_out;  // [T,1,1024] f32; holds xw between phases

    ull* hbuf = (ull*)d_ws;  // 2 * 32 * 512 * 8B = 256 KiB (replicated)
    const size_t hbytes = (size_t)2 * NB_SCAN * WORDS * sizeof(ull);
    int* quit = (int*)((char*)d_ws + hbytes);
    hipMemsetAsync(d_ws, 0, hbytes + 128, stream);

    dim3 ggrid(HID / 128, T_STEPS / 128);
    gemm_xw<<<ggrid, 256, 0, stream>>>(x, wih, out);

    scan_rnn<<<NB_SCAN + NB_HEAT, 256, 0, stream>>>(whh, wgt, bih, bhh, bb,
                                                    out, hbuf, quit);
}